// Round 1
// baseline (243.031 us; speedup 1.0000x reference)
//
#include <hip/hip_runtime.h>
#include <hip/hip_bf16.h>

// SelfAttention: N=8192, D_IN=512, D_K=64, fp32 in/out.
// Scheme:
//   K0: split W (fp32 -> bf16 hi/lo)                    [tiny]
//   K1: QKV projection, split-bf16 MFMA (hh+hl+lh)      -> q_hi/q_lo/k_hi/k_lo [8192x64] bf16, Vt [64x8192] bf16
//   K2: flash attention, 256 blocks x 8 waves; 32 q/block, keys split 8-way across waves;
//       QK^T in split-bf16 (6 MFMA per 16x16 tile pair), online softmax, PV in bf16,
//       LDS merge of 8 per-wave partials (m, l, O).
// Numerics: score error ~0.02 (split-bf16) << 0.3 budget; bf16 P/V/Om adds ~0.15 abs.

#define N_TOK 8192
#define D_INN 512
#define DK    64

typedef __attribute__((ext_vector_type(8))) short bf16x8;
typedef __attribute__((ext_vector_type(4))) float f32x4;

__device__ __forceinline__ unsigned short f2bf(float f) {
  union { float f; unsigned u; } v; v.f = f;
  unsigned r = v.u + 0x7FFFu + ((v.u >> 16) & 1u);
  return (unsigned short)(r >> 16);
}
__device__ __forceinline__ float bf2f(unsigned short h) {
  union { unsigned u; float f; } v; v.u = ((unsigned)h) << 16;
  return v.f;
}

// ---------------- K0: split weights into bf16 hi/lo ----------------
__global__ __launch_bounds__(256) void prep_w_kernel(
    const float* __restrict__ Wq, const float* __restrict__ Wk, const float* __restrict__ Wv,
    unsigned short* __restrict__ w_hi, unsigned short* __restrict__ w_lo) {
  int t = blockIdx.x * 256 + threadIdx.x;
  if (t >= 192 * 512) return;
  const float* src = (t < 64 * 512) ? Wq : ((t < 128 * 512) ? Wk : Wv);
  float x = src[t & (64 * 512 - 1)];
  unsigned short h = f2bf(x);
  w_hi[t] = h;
  w_lo[t] = f2bf(x - bf2f(h));
}

// ---------------- K1: QKV projection (split-bf16 MFMA) ----------------
// grid 512 x 64 threads (1 wave). Each wave: 16 rows x 192 cols, K=512.
__global__ __launch_bounds__(64) void qkv_kernel(
    const float* __restrict__ X,
    const unsigned short* __restrict__ w_hi, const unsigned short* __restrict__ w_lo,
    unsigned short* __restrict__ q_hi, unsigned short* __restrict__ q_lo,
    unsigned short* __restrict__ k_hi, unsigned short* __restrict__ k_lo,
    unsigned short* __restrict__ vt) {
  const int l = threadIdx.x;
  const int l15 = l & 15, g = l >> 4;
  const int row0 = blockIdx.x * 16;

  f32x4 acc[12];
#pragma unroll
  for (int s = 0; s < 12; s++) acc[s] = f32x4{0.f, 0.f, 0.f, 0.f};

  for (int kc = 0; kc < D_INN; kc += 32) {
    const float* xp = X + (row0 + l15) * D_INN + kc + g * 8;
    float4 t0 = *(const float4*)xp;
    float4 t1 = *(const float4*)(xp + 4);
    float av[8] = {t0.x, t0.y, t0.z, t0.w, t1.x, t1.y, t1.z, t1.w};
    bf16x8 ah, al;
#pragma unroll
    for (int i = 0; i < 8; i++) {
      unsigned short h = f2bf(av[i]);
      ((unsigned short*)&ah)[i] = h;
      ((unsigned short*)&al)[i] = f2bf(av[i] - bf2f(h));
    }
#pragma unroll
    for (int s = 0; s < 12; s++) {
      const unsigned short* wph = w_hi + (s * 16 + l15) * D_INN + kc + g * 8;
      const unsigned short* wpl = w_lo + (s * 16 + l15) * D_INN + kc + g * 8;
      bf16x8 bh = *(const bf16x8*)wph;
      bf16x8 bl = *(const bf16x8*)wpl;
      acc[s] = __builtin_amdgcn_mfma_f32_16x16x32_bf16(ah, bh, acc[s], 0, 0, 0);
      acc[s] = __builtin_amdgcn_mfma_f32_16x16x32_bf16(ah, bl, acc[s], 0, 0, 0);
      acc[s] = __builtin_amdgcn_mfma_f32_16x16x32_bf16(al, bh, acc[s], 0, 0, 0);
    }
  }

#pragma unroll
  for (int s = 0; s < 12; s++) {
    if (s < 8) {
      unsigned short* hi = (s < 4) ? q_hi : k_hi;
      unsigned short* lo = (s < 4) ? q_lo : k_lo;
      int col = (s & 3) * 16 + l15;
#pragma unroll
      for (int r = 0; r < 4; r++) {
        int row = row0 + g * 4 + r;
        float v = acc[s][r];
        unsigned short h = f2bf(v);
        hi[row * DK + col] = h;
        lo[row * DK + col] = f2bf(v - bf2f(h));
      }
    } else {
      int d = (s - 8) * 16 + l15;
      unsigned short pk[4];
#pragma unroll
      for (int r = 0; r < 4; r++) pk[r] = f2bf(acc[s][r]);
      // Vt[d][row0 + g*4 .. +3], 8B store
      *(uint2*)(vt + d * N_TOK + row0 + g * 4) = *(const uint2*)pk;
    }
  }
}

// ---------------- K2: flash attention ----------------
// grid 256 x 512 threads (8 waves). Block: 32 queries; wave w: keys [w*1024, (w+1)*1024).
__global__ __launch_bounds__(512) void attn_kernel(
    const unsigned short* __restrict__ q_hi, const unsigned short* __restrict__ q_lo,
    const unsigned short* __restrict__ k_hi, const unsigned short* __restrict__ k_lo,
    const unsigned short* __restrict__ vt, float* __restrict__ out) {
  extern __shared__ char smem[];
  unsigned short* P_lds = (unsigned short*)smem;            // [8 waves][16][72]
  unsigned short* OmS   = (unsigned short*)(smem + 18432);  // [8][32][64] bf16 partial O
  float* Mw = (float*)(smem + 18432 + 32768);               // [8][32]
  float* Lw = Mw + 8 * 32;                                  // [8][32]

  const int tid = threadIdx.x;
  const int l = tid & 63, wid = tid >> 6;
  const int l15 = l & 15, g = l >> 4;
  const int qb = blockIdx.x * 32;

  // Q fragments (A-layout), split hi/lo, 2 q-subtiles x 2 k-chunks
  bf16x8 qh[2][2], ql[2][2];
#pragma unroll
  for (int u = 0; u < 2; u++)
#pragma unroll
    for (int c = 0; c < 2; c++) {
      int row = qb + u * 16 + l15;
      qh[u][c] = *(const bf16x8*)(q_hi + row * DK + c * 32 + g * 8);
      ql[u][c] = *(const bf16x8*)(q_lo + row * DK + c * 32 + g * 8);
    }

  float m[2][4], ln[2][4];
  f32x4 accO[2][4];
#pragma unroll
  for (int u = 0; u < 2; u++)
#pragma unroll
    for (int r = 0; r < 4; r++) { m[u][r] = -1e30f; ln[u][r] = 0.f; }
#pragma unroll
  for (int u = 0; u < 2; u++)
#pragma unroll
    for (int ds = 0; ds < 4; ds++) accO[u][ds] = f32x4{0.f, 0.f, 0.f, 0.f};

  const int k0 = wid * (N_TOK / 8);
  for (int kt = k0; kt < k0 + N_TOK / 8; kt += 64) {
    // ---- S = Q K^T / 8 for 64 keys (4 subtiles), both q-subtiles ----
    float st[2][4][4];
#pragma unroll
    for (int s = 0; s < 4; s++) {
      bf16x8 kh[2], kl[2];
#pragma unroll
      for (int c = 0; c < 2; c++) {
        int krow = kt + s * 16 + l15;
        kh[c] = *(const bf16x8*)(k_hi + krow * DK + c * 32 + g * 8);
        kl[c] = *(const bf16x8*)(k_lo + krow * DK + c * 32 + g * 8);
      }
#pragma unroll
      for (int u = 0; u < 2; u++) {
        f32x4 sa = f32x4{0.f, 0.f, 0.f, 0.f};
        sa = __builtin_amdgcn_mfma_f32_16x16x32_bf16(qh[u][0], kh[0], sa, 0, 0, 0);
        sa = __builtin_amdgcn_mfma_f32_16x16x32_bf16(qh[u][1], kh[1], sa, 0, 0, 0);
        sa = __builtin_amdgcn_mfma_f32_16x16x32_bf16(qh[u][0], kl[0], sa, 0, 0, 0);
        sa = __builtin_amdgcn_mfma_f32_16x16x32_bf16(qh[u][1], kl[1], sa, 0, 0, 0);
        sa = __builtin_amdgcn_mfma_f32_16x16x32_bf16(ql[u][0], kh[0], sa, 0, 0, 0);
        sa = __builtin_amdgcn_mfma_f32_16x16x32_bf16(ql[u][1], kh[1], sa, 0, 0, 0);
#pragma unroll
        for (int r = 0; r < 4; r++) st[u][s][r] = sa[r] * 0.125f;
      }
    }

    // ---- online softmax + P->LDS transpose + A-frag read, per q-subtile ----
    bf16x8 pa[2][2];
#pragma unroll
    for (int u = 0; u < 2; u++) {
      float tmax[4];
#pragma unroll
      for (int r = 0; r < 4; r++) {
        float t = fmaxf(fmaxf(st[u][0][r], st[u][1][r]), fmaxf(st[u][2][r], st[u][3][r]));
#pragma unroll
        for (int off = 1; off < 16; off <<= 1) t = fmaxf(t, __shfl_xor(t, off, 64));
        tmax[r] = t;
      }
#pragma unroll
      for (int r = 0; r < 4; r++) {
        float mn = fmaxf(m[u][r], tmax[r]);
        float fac = __expf(m[u][r] - mn);
        m[u][r] = mn;
        ln[u][r] *= fac;
#pragma unroll
        for (int ds = 0; ds < 4; ds++) accO[u][ds][r] *= fac;
      }
      float rsum[4] = {0.f, 0.f, 0.f, 0.f};
#pragma unroll
      for (int s = 0; s < 4; s++) {
#pragma unroll
        for (int r = 0; r < 4; r++) {
          float p = __expf(st[u][s][r] - m[u][r]);
          rsum[r] += p;
          P_lds[(wid * 16 + g * 4 + r) * 72 + s * 16 + l15] = f2bf(p);
        }
      }
#pragma unroll
      for (int r = 0; r < 4; r++) {
        float t = rsum[r];
#pragma unroll
        for (int off = 1; off < 16; off <<= 1) t += __shfl_xor(t, off, 64);
        ln[u][r] += t;
      }
      // A-fragment read of P (same wave; LDS ops are in-order within a wave)
#pragma unroll
      for (int c = 0; c < 2; c++)
        pa[u][c] = *(const bf16x8*)&P_lds[(wid * 16 + l15) * 72 + c * 32 + g * 8];
    }

    // ---- PV ----
#pragma unroll
    for (int ds = 0; ds < 4; ds++) {
      bf16x8 vb[2];
#pragma unroll
      for (int c = 0; c < 2; c++)
        vb[c] = *(const bf16x8*)(vt + (ds * 16 + l15) * N_TOK + kt + c * 32 + g * 8);
#pragma unroll
      for (int u = 0; u < 2; u++) {
        accO[u][ds] = __builtin_amdgcn_mfma_f32_16x16x32_bf16(pa[u][0], vb[0], accO[u][ds], 0, 0, 0);
        accO[u][ds] = __builtin_amdgcn_mfma_f32_16x16x32_bf16(pa[u][1], vb[1], accO[u][ds], 0, 0, 0);
      }
    }
  }

  // ---- write per-wave partials ----
#pragma unroll
  for (int u = 0; u < 2; u++) {
#pragma unroll
    for (int ds = 0; ds < 4; ds++)
#pragma unroll
      for (int r = 0; r < 4; r++)
        OmS[(wid * 32 + u * 16 + g * 4 + r) * 64 + ds * 16 + l15] = f2bf(accO[u][ds][r]);
    if (l15 == 0) {
#pragma unroll
      for (int r = 0; r < 4; r++) {
        Mw[wid * 32 + u * 16 + g * 4 + r] = m[u][r];
        Lw[wid * 32 + u * 16 + g * 4 + r] = ln[u][r];
      }
    }
  }
  __syncthreads();

  // ---- merge 8 key-split partials ----
  for (int i = tid; i < 32 * 64; i += 512) {
    int q = i >> 6, d = i & 63;
    float M = -1e30f;
#pragma unroll
    for (int w = 0; w < 8; w++) M = fmaxf(M, Mw[w * 32 + q]);
    float num = 0.f, den = 0.f;
#pragma unroll
    for (int w = 0; w < 8; w++) {
      float e = __expf(Mw[w * 32 + q] - M);
      num += bf2f(OmS[(w * 32 + q) * 64 + d]) * e;
      den += Lw[w * 32 + q] * e;
    }
    out[(qb + q) * DK + d] = num / den;
  }
}

// ---------------- host launch ----------------
extern "C" void kernel_launch(void* const* d_in, const int* in_sizes, int n_in,
                              void* d_out, int out_size, void* d_ws, size_t ws_size,
                              hipStream_t stream) {
  (void)in_sizes; (void)n_in; (void)out_size; (void)ws_size;
  const float* X  = (const float*)d_in[0];
  const float* Wq = (const float*)d_in[1];
  const float* Wk = (const float*)d_in[2];
  const float* Wv = (const float*)d_in[3];

  unsigned short* ws = (unsigned short*)d_ws;
  unsigned short* q_hi = ws;                       // 8192*64
  unsigned short* q_lo = q_hi + N_TOK * DK;
  unsigned short* k_hi = q_lo + N_TOK * DK;
  unsigned short* k_lo = k_hi + N_TOK * DK;
  unsigned short* vt   = k_lo + N_TOK * DK;        // 64*8192
  unsigned short* w_hi = vt + DK * N_TOK;          // 192*512
  unsigned short* w_lo = w_hi + 192 * 512;

  prep_w_kernel<<<384, 256, 0, stream>>>(Wq, Wk, Wv, w_hi, w_lo);
  qkv_kernel<<<N_TOK / 16, 64, 0, stream>>>(X, w_hi, w_lo, q_hi, q_lo, k_hi, k_lo, vt);
  attn_kernel<<<N_TOK / 32, 512, 18432 + 32768 + 2048, stream>>>(q_hi, q_lo, k_hi, k_lo, vt, (float*)d_out);
}